// Round 6
// baseline (69.169 us; speedup 1.0000x reference)
//
#include <hip/hip_runtime.h>

// Bahdanau additive attention, f32. B=8, TQ=128, TK=512, NIN=512, H=128, NV=512.
// out = [context (B*TQ*NV), attn (B*TQ*TK)] f32.

#define B_    8
#define TQ_   128
#define TK_   512
#define NIN_  512
#define H_    128
#define NV_   512
#define NQR   (B_*TQ_)           // 1024 query rows
#define NROWS (NQR + B_*TK_)     // 5120 total projected rows

#define C2_   2.8853900817779268f   // 2*log2(e)
#define L2E_  1.4426950408889634f

__device__ __forceinline__ float fexp2(float x){ return __builtin_amdgcn_exp2f(x); }
__device__ __forceinline__ float frcp (float x){ return __builtin_amdgcn_rcpf(x); }

// ---------------------------------------------------------------- proj ----
// psum[s][row][h] = A[row, ks:ke) . W[h, ks:ke)
// 128 threads, tile 16 rows x 128 h, 4x4 microtile (VALU-bound inner loop),
// K-chunk 32, split-K=4. grid (320, 4) = 1280 blocks = 10 waves/CU.
__global__ __launch_bounds__(128, 4) void proj_kernel(
        const float* __restrict__ query, const float* __restrict__ keys,
        const float* __restrict__ Wq, const float* __restrict__ Wk,
        float* __restrict__ psum, int kper) {
    __shared__ float at[32][20];     // [kk][row], 16 rows
    __shared__ float wt[32][132];    // [kk][h]
    const int tid = threadIdx.x;
    const int r0  = blockIdx.x * 16;
    const float* in; const float* W;
    if (r0 < NQR) { in = query + (size_t)r0 * NIN_;         W = Wq; }
    else          { in = keys  + (size_t)(r0 - NQR) * NIN_; W = Wk; }

    const int r4 = (tid >> 5) * 4;       // 4 rows
    const int h4 = (tid & 31) * 4;       // 4 h
    const int sr  = tid >> 3;            // stage row 0..15
    const int skq = (tid & 7) * 4;       // stage k quad
    const int kb0 = blockIdx.y * kper;
    const int nc  = kper >> 5;

    const float* pA = in + sr * NIN_ + kb0 + skq;
    const float* pW0 = W + (sr      ) * NIN_ + kb0 + skq;
    const float* pW1 = W + (sr + 16 ) * NIN_ + kb0 + skq;
    const float* pW2 = W + (sr + 32 ) * NIN_ + kb0 + skq;
    const float* pW3 = W + (sr + 48 ) * NIN_ + kb0 + skq;
    const float* pW4 = W + (sr + 64 ) * NIN_ + kb0 + skq;
    const float* pW5 = W + (sr + 80 ) * NIN_ + kb0 + skq;
    const float* pW6 = W + (sr + 96 ) * NIN_ + kb0 + skq;
    const float* pW7 = W + (sr + 112) * NIN_ + kb0 + skq;

    float4 af  = *(const float4*)pA;
    float4 w0 = *(const float4*)pW0, w1 = *(const float4*)pW1;
    float4 w2 = *(const float4*)pW2, w3 = *(const float4*)pW3;
    float4 w4 = *(const float4*)pW4, w5 = *(const float4*)pW5;
    float4 w6 = *(const float4*)pW6, w7 = *(const float4*)pW7;

    float acc[4][4];
#pragma unroll
    for (int i = 0; i < 4; ++i)
#pragma unroll
        for (int j = 0; j < 4; ++j) acc[i][j] = 0.0f;

    for (int c = 0; c < nc; ++c) {
        __syncthreads();
        at[skq+0][sr] = af.x; at[skq+1][sr] = af.y;
        at[skq+2][sr] = af.z; at[skq+3][sr] = af.w;
        wt[skq+0][sr    ] = w0.x; wt[skq+1][sr    ] = w0.y;
        wt[skq+2][sr    ] = w0.z; wt[skq+3][sr    ] = w0.w;
        wt[skq+0][sr+ 16] = w1.x; wt[skq+1][sr+ 16] = w1.y;
        wt[skq+2][sr+ 16] = w1.z; wt[skq+3][sr+ 16] = w1.w;
        wt[skq+0][sr+ 32] = w2.x; wt[skq+1][sr+ 32] = w2.y;
        wt[skq+2][sr+ 32] = w2.z; wt[skq+3][sr+ 32] = w2.w;
        wt[skq+0][sr+ 48] = w3.x; wt[skq+1][sr+ 48] = w3.y;
        wt[skq+2][sr+ 48] = w3.z; wt[skq+3][sr+ 48] = w3.w;
        wt[skq+0][sr+ 64] = w4.x; wt[skq+1][sr+ 64] = w4.y;
        wt[skq+2][sr+ 64] = w4.z; wt[skq+3][sr+ 64] = w4.w;
        wt[skq+0][sr+ 80] = w5.x; wt[skq+1][sr+ 80] = w5.y;
        wt[skq+2][sr+ 80] = w5.z; wt[skq+3][sr+ 80] = w5.w;
        wt[skq+0][sr+ 96] = w6.x; wt[skq+1][sr+ 96] = w6.y;
        wt[skq+2][sr+ 96] = w6.z; wt[skq+3][sr+ 96] = w6.w;
        wt[skq+0][sr+112] = w7.x; wt[skq+1][sr+112] = w7.y;
        wt[skq+2][sr+112] = w7.z; wt[skq+3][sr+112] = w7.w;
        __syncthreads();
        if (c + 1 < nc) {
            pA += 32; pW0 += 32; pW1 += 32; pW2 += 32; pW3 += 32;
            pW4 += 32; pW5 += 32; pW6 += 32; pW7 += 32;
            af = *(const float4*)pA;
            w0 = *(const float4*)pW0; w1 = *(const float4*)pW1;
            w2 = *(const float4*)pW2; w3 = *(const float4*)pW3;
            w4 = *(const float4*)pW4; w5 = *(const float4*)pW5;
            w6 = *(const float4*)pW6; w7 = *(const float4*)pW7;
        }
#pragma unroll 8
        for (int kk = 0; kk < 32; ++kk) {
            float4 a = *(const float4*)&at[kk][r4];
            float4 w = *(const float4*)&wt[kk][h4];
            float av[4] = {a.x, a.y, a.z, a.w};
            float wv[4] = {w.x, w.y, w.z, w.w};
#pragma unroll
            for (int i = 0; i < 4; ++i)
#pragma unroll
                for (int j = 0; j < 4; ++j)
                    acc[i][j] = fmaf(av[i], wv[j], acc[i][j]);
        }
    }

    float* op = psum + ((size_t)blockIdx.y * NROWS + r0) * H_;
#pragma unroll
    for (int i = 0; i < 4; ++i) {
        float4 o = {acc[i][0], acc[i][1], acc[i][2], acc[i][3]};
        *(float4*)&op[(r4 + i) * H_ + h4] = o;
    }
}

// -------------------------------------------------------------- reduce ----
// Per block: 8 rows. Sum 4 psum splits + bias.
// q-rows -> qp row-major. k-rows -> kpT[b][h][k] (transposed, *C2 folded).
// grid 640 blocks.
__global__ __launch_bounds__(256, 4) void reduce_kernel(
        const float* __restrict__ psum, const float* __restrict__ bq,
        const float* __restrict__ bk, float* __restrict__ qp,
        float* __restrict__ kpT) {
    __shared__ float lt[128][9];
    const int tid = threadIdx.x;
    const int r0  = blockIdx.x * 8;
    const bool isq = (r0 < NQR);
    const float* bias = isq ? bq : bk;

    const int row = tid >> 5, hq = (tid & 31) * 4;   // [8 rows][32 h-quads]
    const float4 b4 = *(const float4*)&bias[hq];
    float4 s = b4;
#pragma unroll
    for (int sp = 0; sp < 4; ++sp) {
        float4 v = *(const float4*)&psum[((size_t)sp * NROWS + r0 + row) * H_ + hq];
        s.x += v.x; s.y += v.y; s.z += v.z; s.w += v.w;
    }
    if (isq) {
        *(float4*)&qp[(size_t)(r0 + row) * H_ + hq] = s;
    } else {
        lt[hq + 0][row] = s.x * C2_; lt[hq + 1][row] = s.y * C2_;
        lt[hq + 2][row] = s.z * C2_; lt[hq + 3][row] = s.w * C2_;
        __syncthreads();
        const int b  = (r0 - NQR) >> 9;
        const int k0 = (r0 - NQR) & 511;
        const int h = tid >> 1, kq = (tid & 1) * 4;  // [128 h][2 k-quads]
        float4 o = {lt[h][kq], lt[h][kq + 1], lt[h][kq + 2], lt[h][kq + 3]};
        *(float4*)&kpT[((size_t)b * H_ + h) * TK_ + k0 + kq] = o;
    }
}

// -------------------------------------------------------------- scores ----
// Per block: batch b, 2 q rows. Thread = (1 q, 4 k); k contiguous via kpT.
// score = bo + sumWo - 2*sum_h Wo_h/(e^(2x_h)+1)
__global__ __launch_bounds__(256, 4) void scores_kernel(
        const float* __restrict__ qp, const float* __restrict__ kpT,
        const float* __restrict__ Wo, const float* __restrict__ bo,
        float* __restrict__ out_attn) {
    __shared__ float qs2[2][H_];    // q_proj * C2
    __shared__ float w2[H_];        // -2 * Wo
    __shared__ float sc[2][TK_];

    const int tid = threadIdx.x;
    const int b   = blockIdx.y;
    const int q0  = blockIdx.x * 2;
    const int lane = tid & 63;

    qs2[tid >> 7][tid & 127] =
        qp[(b * TQ_ + q0 + (tid >> 7)) * H_ + (tid & 127)] * C2_;
    if (tid < H_) w2[tid] = Wo[tid] * -2.0f;
    __syncthreads();

    float sw = w2[lane] + w2[lane + 64];
#pragma unroll
    for (int m = 1; m < 64; m <<= 1) sw += __shfl_xor(sw, m);
    const float sbase = bo[0] - 0.5f * sw;

    const int k4 = (tid & 127) * 4;        // 4 k's per thread
    const int qi = tid >> 7;               // q row 0/1
    const float* pk = kpT + (size_t)b * H_ * TK_ + k4;
    float a0 = 0.f, a1 = 0.f, a2 = 0.f, a3 = 0.f;
#pragma unroll 4
    for (int h = 0; h < H_; ++h) {
        float4 kv = *(const float4*)pk;
        pk += TK_;
        const float qv = qs2[qi][h];
        const float wv = w2[h];
        a0 = fmaf(wv, frcp(fexp2(qv + kv.x) + 1.0f), a0);
        a1 = fmaf(wv, frcp(fexp2(qv + kv.y) + 1.0f), a1);
        a2 = fmaf(wv, frcp(fexp2(qv + kv.z) + 1.0f), a2);
        a3 = fmaf(wv, frcp(fexp2(qv + kv.w) + 1.0f), a3);
    }
    float4 sv = {a0 + sbase, a1 + sbase, a2 + sbase, a3 + sbase};
    *(float4*)&sc[qi][k4] = sv;
    __syncthreads();

    const int w = tid >> 6;
    if (w < 2) {
        float4 sA = *(const float4*)&sc[w][lane * 8];
        float4 sB = *(const float4*)&sc[w][lane * 8 + 4];
        float m = fmaxf(fmaxf(fmaxf(sA.x, sA.y), fmaxf(sA.z, sA.w)),
                        fmaxf(fmaxf(sB.x, sB.y), fmaxf(sB.z, sB.w)));
#pragma unroll
        for (int mask = 1; mask < 64; mask <<= 1) m = fmaxf(m, __shfl_xor(m, mask));
        float4 eA, eB;
        eA.x = fexp2((sA.x - m) * L2E_); eA.y = fexp2((sA.y - m) * L2E_);
        eA.z = fexp2((sA.z - m) * L2E_); eA.w = fexp2((sA.w - m) * L2E_);
        eB.x = fexp2((sB.x - m) * L2E_); eB.y = fexp2((sB.y - m) * L2E_);
        eB.z = fexp2((sB.z - m) * L2E_); eB.w = fexp2((sB.w - m) * L2E_);
        float s = eA.x + eA.y + eA.z + eA.w + eB.x + eB.y + eB.z + eB.w;
#pragma unroll
        for (int mask = 1; mask < 64; mask <<= 1) s += __shfl_xor(s, mask);
        float inv = frcp(s);
        eA.x *= inv; eA.y *= inv; eA.z *= inv; eA.w *= inv;
        eB.x *= inv; eB.y *= inv; eB.z *= inv; eB.w *= inv;
        float4* op = (float4*)&out_attn[(b * TQ_ + q0 + w) * TK_ + lane * 8];
        op[0] = eA; op[1] = eB;
    }
}

// ------------------------------------------------------------- context ----
// 128 threads, tile 8 q x 64 v, full K=512, 2x2 microtile, reg prefetch.
// grid (128 = 16 q-tiles x 8 v-tiles, B) = 1024 blocks = 8 waves/CU.
__global__ __launch_bounds__(128, 4) void context_kernel(
        const float* __restrict__ attn, const float* __restrict__ values,
        float* __restrict__ outc) {
    __shared__ float at[32][12];    // [kk][q], 8 q
    __shared__ float vt[32][68];    // [kk][v], 64 v

    const int tid = threadIdx.x;
    const int b   = blockIdx.y;
    const int q0  = (blockIdx.x >> 3) * 8;
    const int v0  = (blockIdx.x & 7) * 64;

    const int v2 = (tid & 31) * 2;          // 2 v
    const int q2 = (tid >> 5) * 2;          // 2 q
    const int ar  = tid >> 3;               // attn stage row (tid<64: 0..7)
    const int akq = (tid & 7) * 4;
    const int vr  = tid >> 4;               // values stage row 0..7 (+8p)
    const int vq  = (tid & 15) * 4;

    const float* pAt = attn + (size_t)(b * TQ_ + q0 + ar) * TK_ + akq;
    const float* pV0 = values + (size_t)(b * TK_ + vr     ) * NV_ + v0 + vq;
    const float* pV1 = values + (size_t)(b * TK_ + vr +  8) * NV_ + v0 + vq;
    const float* pV2 = values + (size_t)(b * TK_ + vr + 16) * NV_ + v0 + vq;
    const float* pV3 = values + (size_t)(b * TK_ + vr + 24) * NV_ + v0 + vq;

    float4 af = {0.f,0.f,0.f,0.f};
    if (tid < 64) af = *(const float4*)pAt;
    float4 vf0 = *(const float4*)pV0;
    float4 vf1 = *(const float4*)pV1;
    float4 vf2 = *(const float4*)pV2;
    float4 vf3 = *(const float4*)pV3;

    float acc[2][2] = {{0.f,0.f},{0.f,0.f}};

    for (int c = 0; c < 16; ++c) {
        __syncthreads();
        if (tid < 64) {
            at[akq+0][ar] = af.x; at[akq+1][ar] = af.y;
            at[akq+2][ar] = af.z; at[akq+3][ar] = af.w;
        }
        *(float4*)&vt[vr     ][vq] = vf0;
        *(float4*)&vt[vr +  8][vq] = vf1;
        *(float4*)&vt[vr + 16][vq] = vf2;
        *(float4*)&vt[vr + 24][vq] = vf3;
        __syncthreads();
        if (c + 1 < 16) {
            pAt += 32; pV0 += 32 * NV_; pV1 += 32 * NV_;
            pV2 += 32 * NV_; pV3 += 32 * NV_;
            if (tid < 64) af = *(const float4*)pAt;
            vf0 = *(const float4*)pV0; vf1 = *(const float4*)pV1;
            vf2 = *(const float4*)pV2; vf3 = *(const float4*)pV3;
        }
#pragma unroll 8
        for (int kk = 0; kk < 32; ++kk) {
            float2 a = *(const float2*)&at[kk][q2];
            float2 v = *(const float2*)&vt[kk][v2];
            acc[0][0] = fmaf(a.x, v.x, acc[0][0]);
            acc[0][1] = fmaf(a.x, v.y, acc[0][1]);
            acc[1][0] = fmaf(a.y, v.x, acc[1][0]);
            acc[1][1] = fmaf(a.y, v.y, acc[1][1]);
        }
    }
    float2 o0 = {acc[0][0], acc[0][1]};
    float2 o1 = {acc[1][0], acc[1][1]};
    *(float2*)&outc[(size_t)(b * TQ_ + q0 + q2 + 0) * NV_ + v0 + v2] = o0;
    *(float2*)&outc[(size_t)(b * TQ_ + q0 + q2 + 1) * NV_ + v0 + v2] = o1;
}

// -------------------------------------------------------------- launch ----
extern "C" void kernel_launch(void* const* d_in, const int* in_sizes, int n_in,
                              void* d_out, int out_size, void* d_ws, size_t ws_size,
                              hipStream_t stream) {
    const float* query  = (const float*)d_in[0];
    const float* keys   = (const float*)d_in[1];
    const float* values = (const float*)d_in[2];
    const float* Wq     = (const float*)d_in[3];
    const float* bq     = (const float*)d_in[4];
    const float* Wk     = (const float*)d_in[5];
    const float* bk     = (const float*)d_in[6];
    const float* Wo     = (const float*)d_in[7];
    const float* bo     = (const float*)d_in[8];

    float* out_ctx  = (float*)d_out;                 // B*TQ*NV
    float* out_attn = out_ctx + B_ * TQ_ * NV_;      // B*TQ*TK
    float* qp   = (float*)d_ws;                      // NQR*H
    float* kpT  = qp + (size_t)NQR * H_;             // B*H*TK (transposed, *C2)
    float* psum = kpT + (size_t)B_ * H_ * TK_;       // 4*NROWS*H

    proj_kernel<<<dim3(NROWS / 16, 4), 128, 0, stream>>>(
        query, keys, Wq, Wk, psum, NIN_ / 4);
    reduce_kernel<<<NROWS / 8, 256, 0, stream>>>(psum, bq, bk, qp, kpT);
    scores_kernel<<<dim3(TQ_ / 2, B_), 256, 0, stream>>>(qp, kpT, Wo, bo, out_attn);
    context_kernel<<<dim3(128, B_), 128, 0, stream>>>(out_attn, values, out_ctx);
}